// Round 17
// baseline (2371.303 us; speedup 1.0000x reference)
//
#include <hip/hip_runtime.h>

#define NQ 273

typedef float f4 __attribute__((ext_vector_type(4)));

// ---------------- compile-time GA tables (Cl(3,0,1) PGA, 16 blades) ----------------
struct GATab {
  int qi[NQ]; int qj[NQ]; int qk[NQ];
  float qs[NQ];
  int qgp[NQ];
  int qpath[NQ];
  int qnew[NQ];   // 1 if this term's coef index differs from previous (after sort)
  int ngp, njp, nq;
};

constexpr int popc4(int m){ int c=0; for(int b=0;b<5;++b) c+=(m>>b)&1; return c; }
constexpr int swap_par(int a,int b){ int s=0; a>>=1; while(a){ s+=popc4(a&b); a>>=1; } return s&1; }

constexpr GATab make_tab(){
  GATab t{};
  int bladeOf[16]={}; int idxOf[16]={};
  { int p=0;
    for(int g=0; g<=4; ++g)
      for(int m=0; m<16; ++m)
        if(popc4(m)==g){ bladeOf[p]=m; idxOf[m]=p; ++p; }
  }
  int grade[16]={};
  for(int j=0;j<16;++j) grade[j]=popc4(bladeOf[j]);
  bool gpp[125]={}; bool jpp[125]={};
  for(int j=0;j<16;++j) for(int k=0;k<16;++k){
    int mj=bladeOf[j], mk=bladeOf[k];
    if(!(mj&mk&1)){ int i=idxOf[mj^mk]; gpp[(grade[i]*5+grade[j])*5+grade[k]]=true; }
    int cj=15^mj, ck=15^mk;
    if(!(cj&ck)){ int r=mj&mk; int i=idxOf[r]; jpp[(grade[i]*5+grade[j])*5+grade[k]]=true; }
  }
  int gpidx[125]={}; int jpidx[125]={};
  { int c=0; for(int u=0;u<125;++u){ gpidx[u] = gpp[u]? c++ : -1; } t.ngp=c; }
  { int c=0; for(int u=0;u<125;++u){ jpidx[u] = jpp[u]? c++ : -1; } t.njp=c; }
  int q=0;
  for(int j=0;j<16;++j) for(int k=0;k<16;++k){
    int mj=bladeOf[j], mk=bladeOf[k];
    if(!(mj&mk&1)){
      int i=idxOf[mj^mk];
      t.qi[q]=i; t.qj[q]=j; t.qk[q]=k;
      t.qs[q] = swap_par(mj,mk) ? -1.0f : 1.0f;
      t.qgp[q]=1;
      t.qpath[q]=gpidx[(grade[i]*5+grade[j])*5+grade[k]];
      ++q;
    }
  }
  for(int j=0;j<16;++j) for(int k=0;k<16;++k){
    int mj=bladeOf[j], mk=bladeOf[k];
    int cj=15^mj, ck=15^mk;
    if(!(cj&ck)){
      int r=mj&mk; int i=idxOf[r];
      int par = swap_par(mj,15^mj) ^ swap_par(mk,15^mk) ^ swap_par(cj,ck) ^ swap_par(r,15^r);
      t.qi[q]=i; t.qj[q]=j; t.qk[q]=k;
      t.qs[q] = par ? -1.0f : 1.0f;
      t.qgp[q]=0;
      t.qpath[q]=jpidx[(grade[i]*5+grade[j])*5+grade[k]];
      ++q;
    }
  }
  t.nq=q;

  // sort terms by coef index (gp paths first, then jp) so terms sharing one
  // coef value are adjacent -> ONE rolling-register LDS read per unique coef.
  for(int a=1;a<t.nq;++a){
    int ci=t.qi[a], cj2=t.qj[a], ck2=t.qk[a], cg=t.qgp[a], cp=t.qpath[a]; float cs=t.qs[a];
    int key = cg ? cp : 1000+cp;
    int b=a-1;
    while(b>=0){
      int kb = t.qgp[b] ? t.qpath[b] : 1000+t.qpath[b];
      if(kb <= key) break;
      t.qi[b+1]=t.qi[b]; t.qj[b+1]=t.qj[b]; t.qk[b+1]=t.qk[b];
      t.qs[b+1]=t.qs[b]; t.qgp[b+1]=t.qgp[b]; t.qpath[b+1]=t.qpath[b];
      --b;
    }
    t.qi[b+1]=ci; t.qj[b+1]=cj2; t.qk[b+1]=ck2; t.qs[b+1]=cs; t.qgp[b+1]=cg; t.qpath[b+1]=cp;
  }
  for(int a=0;a<t.nq;++a){
    if(a==0){ t.qnew[a]=1; continue; }
    int ka = t.qgp[a]   ? t.qpath[a]   : 1000+t.qpath[a];
    int kb = t.qgp[a-1] ? t.qpath[a-1] : 1000+t.qpath[a-1];
    t.qnew[a] = (ka!=kb) ? 1 : 0;
  }
  return t;
}

constexpr GATab TAB = make_tab();
static_assert(TAB.nq == NQ, "nonzero count mismatch");
static_assert(TAB.ngp > 0 && TAB.njp > 0, "path counts");
constexpr int NGPC = TAB.ngp;
constexpr int NJPC = TAB.njp;
constexpr int GR[16] = {0,1,1,1,1,2,2,2,2,2,2,3,3,3,3,4};

// compact coef tables: odd-padded rows -> per-lane stride odd -> 2-way bank
// aliasing only (free, m136).
constexpr int PADG = (NGPC & 1) ? NGPC : NGPC + 1;
constexpr int PADJ = (NJPC & 1) ? NJPC : NJPC + 1;
constexpr int CGF  = 64 * PADG;          // floats
constexpr int CJF  = 64 * PADJ;          // floats
constexpr int XLF  = 4 * 2 * 64 * 16;    // x staging: 4 waves x NB=2 x (64 i x 16 v) = 32 KB
static_assert((CGF + CJF + XLF) * 4 <= 53 * 1024, "2 blocks/CU headroom check");

// ---------------- prep kernels ----------------
// repack lin_weight (128,64,5) -> wrp[i][n][12]:
//   s in [0,5):  w1 grade s for output channel n      (o = n)
//   s in [5,10): w2 grade s-5 for output channel n+64 (o = 64+n)
//   s in [10,12): pad -> 48 B record, 3x dwordx4 per (i,n)
__global__ void prep_wrp(const float* __restrict__ linw, float* __restrict__ wrp){
  int t = blockIdx.x*blockDim.x + threadIdx.x;
  if(t < 64*64*12){
    int s = t % 12;
    int n = (t/12) & 63;
    int i = t/(12*64);
    float v = 0.f;
    if(s < 5)       v = linw[(n*64 + i)*5 + s];
    else if(s < 10) v = linw[((64+n)*64 + i)*5 + (s-5)];
    wrp[t] = v;
  }
}

// pack gpw/jpw raw into odd-padded rows: cgj[n*PADG+p] , cgj[CGF + n*PADJ+p]
__global__ void prep_cpk(const float* __restrict__ gpw, const float* __restrict__ jpw,
                         float* __restrict__ cgj){
  int n = threadIdx.x; // blockDim = 64, grid = 1
  for(int p=0;p<NGPC;++p) cgj[n*PADG + p] = gpw[n*NGPC + p];
  for(int p=0;p<NJPC;++p) cgj[CGF + n*PADJ + p] = jpw[n*NJPC + p];
}

// ---------------- main fused kernel ----------------
// R16 structure + NB=2 per wave at 256 threads/block.
// Why NB=2 works NOW (3 prior failures, each cause since removed):
//   R9:  273 hoistable coef loads -> sorted rolling-coef + sched_barrier(0x7)
//   R9/R10: 32 xr staging VGPRs   -> x lives in LDS (broadcast reads)
//   R15: 512-thr 128-VGPR cap     -> 256-thr tier is uncapped (R16: chose 68)
// Payoff: the L2 weight stream (192KB x 65536 = 12.6 GB ~ 365us, the binding
// pipe per R16 accounting) HALVES; one weight load + one coef read feed two
// elements. Live set ~100 floats; LDS 53 KB -> 2 blocks/CU x 4 waves.
__global__ __launch_bounds__(256)
void main_k(const float* __restrict__ x, const float* __restrict__ cgj,
            const float* __restrict__ wrp, float* __restrict__ out, int B){
  __shared__ float lds[CGF + CJF + XLF];
  float* clg = lds;
  float* clj = lds + CGF;
  float* xl  = lds + CGF + CJF;

  const int tid  = threadIdx.x;
  const int lane = tid & 63;
  const int wv   = tid >> 6;        // 0..3
  const int n    = lane;

  // ---- stage compact coef tables once per block ----
  for(int idx = tid; idx < CGF + CJF; idx += 256) lds[idx] = cgj[idx];
  __syncthreads();

  const int cgbase = n*PADG;
  const int cjbase = n*PADJ;
  float* xw0 = xl + (wv*2    )*1024;   // element 0 staging (64 i x 16 v)
  float* xw1 = xl + (wv*2 + 1)*1024;   // element 1 staging

  for(int base = blockIdx.x*8; base < B; base += gridDim.x*8){
    const int b0 = base + wv*2;
    const int b1 = b0 + 1;

    // ---- stage x for both elements (swizzled b128 writes, bank-floor) ----
    if(b0 < B){
      const f4* src = (const f4*)(x + ((long)b0*64 + lane)*16);
      #pragma unroll
      for(int r=0;r<4;++r){
        f4 a = __builtin_nontemporal_load(src+r);
        int daddr = (lane*16 + r*4) ^ ((lane&7)<<2);
        *(f4*)(xw0 + daddr) = a;
      }
    }
    if(b1 < B){
      const f4* src = (const f4*)(x + ((long)b1*64 + lane)*16);
      #pragma unroll
      for(int r=0;r<4;++r){
        f4 a = __builtin_nontemporal_load(src+r);
        int daddr = (lane*16 + r*4) ^ ((lane&7)<<2);
        *(f4*)(xw1 + daddr) = a;
      }
    }
    // (per-wave region: in-wave lgkmcnt ordering suffices, no __syncthreads)

    // ---- linear phase: y{1,2}[t][v] = sum_i w{1,2}[g(v)]*x[t][i][v] ----
    float y1[2][16], y2[2][16];
    #pragma unroll
    for(int v=0;v<16;++v){ y1[0][v]=0.f; y1[1][v]=0.f; y2[0][v]=0.f; y2[1][v]=0.f; }

    #pragma unroll 1
    for(int i=0;i<64;++i){
      const f4* wp = (const f4*)(wrp + (i*64 + n)*12);
      f4 wa = wp[0], wb = wp[1], wc = wp[2];
      float w1[5] = {wa[0],wa[1],wa[2],wa[3],wb[0]};
      float w2[5] = {wb[1],wb[2],wb[3],wc[0],wc[1]};

      // broadcast reads of x[t][i][0..15]: uniform address, conflict-free
      #pragma unroll
      for(int g=0;g<4;++g){
        int raddr = (i*16 + g*4) ^ ((i&7)<<2);
        f4 a0 = *(const f4*)(xw0 + raddr);
        f4 a1 = *(const f4*)(xw1 + raddr);
        #pragma unroll
        for(int c=0;c<4;++c){
          int v = g*4+c;
          float g1 = w1[GR[v]], g2 = w2[GR[v]];
          y1[0][v] = fmaf(g1, a0[c], y1[0][v]);
          y2[0][v] = fmaf(g2, a0[c], y2[0][v]);
          y1[1][v] = fmaf(g1, a1[c], y1[1][v]);
          y2[1][v] = fmaf(g2, a1[c], y2[1][v]);
        }
      }
    }

    // ---- bilinear phase: sorted terms, rolling coef register, capped hoist ----
    __builtin_amdgcn_sched_barrier(0x7);
    float acc[2][16];
    #pragma unroll
    for(int v=0;v<16;++v){ acc[0][v]=y2[0][v]; acc[1][v]=y2[1][v]; }

    float c = 0.f;
    #pragma unroll
    for(int q=0;q<NQ;++q){
      if(TAB.qnew[q])
        c = TAB.qgp[q] ? clg[cgbase + TAB.qpath[q]] : clj[cjbase + TAB.qpath[q]];
      float cs = (TAB.qs[q] < 0.f) ? -c : c;
      acc[0][TAB.qi[q]] = fmaf(cs, y1[0][TAB.qj[q]]*y2[0][TAB.qk[q]], acc[0][TAB.qi[q]]);
      acc[1][TAB.qi[q]] = fmaf(cs, y1[1][TAB.qj[q]]*y2[1][TAB.qk[q]], acc[1][TAB.qi[q]]);
      if((q % 24) == 23) __builtin_amdgcn_sched_barrier(0x7);
    }
    __builtin_amdgcn_sched_barrier(0x7);

    // ---- store (streamed once -> nontemporal) ----
    if(b0 < B){
      f4* op = (f4*)(out + ((long)b0*64 + n)*16);
      #pragma unroll
      for(int r=0;r<4;++r){
        f4 o; o[0]=acc[0][4*r]; o[1]=acc[0][4*r+1]; o[2]=acc[0][4*r+2]; o[3]=acc[0][4*r+3];
        __builtin_nontemporal_store(o, op+r);
      }
    }
    if(b1 < B){
      f4* op = (f4*)(out + ((long)b1*64 + n)*16);
      #pragma unroll
      for(int r=0;r<4;++r){
        f4 o; o[0]=acc[1][4*r]; o[1]=acc[1][4*r+1]; o[2]=acc[1][4*r+2]; o[3]=acc[1][4*r+3];
        __builtin_nontemporal_store(o, op+r);
      }
    }
  }
}

extern "C" void kernel_launch(void* const* d_in, const int* in_sizes, int n_in,
                              void* d_out, int out_size, void* d_ws, size_t ws_size,
                              hipStream_t stream){
  const float* x    = (const float*)d_in[0];
  const float* gpw  = (const float*)d_in[1];
  const float* jpw  = (const float*)d_in[2];
  const float* linw = (const float*)d_in[3];
  float* outp = (float*)d_out;

  float* wrp = (float*)d_ws;           // 64*64*12 floats = 192 KB
  float* cgj = wrp + 64*64*12;         // CGF+CJF floats (~21 KB)

  int B = in_sizes[0] / (64*16);

  prep_wrp <<<192, 256, 0, stream>>>(linw, wrp);
  prep_cpk <<<1,   64,  0, stream>>>(gpw, jpw, cgj);
  main_k   <<<2048, 256, 0, stream>>>(x, cgj, wrp, outp, B);
}

// Round 18
// 542.328 us; speedup vs baseline: 4.3725x; 4.3725x over previous
//
#include <hip/hip_runtime.h>

#define NQ 273

typedef float f4 __attribute__((ext_vector_type(4)));
typedef _Float16 hf2 __attribute__((ext_vector_type(2)));

// ---------------- compile-time GA tables (Cl(3,0,1) PGA, 16 blades) ----------------
struct GATab {
  int qi[NQ]; int qj[NQ]; int qk[NQ];
  float qs[NQ];
  int qgp[NQ];
  int qpath[NQ];
  int qnew[NQ];   // 1 if this term's coef index differs from previous (after sort)
  int ngp, njp, nq;
};

constexpr int popc4(int m){ int c=0; for(int b=0;b<5;++b) c+=(m>>b)&1; return c; }
constexpr int swap_par(int a,int b){ int s=0; a>>=1; while(a){ s+=popc4(a&b); a>>=1; } return s&1; }

constexpr GATab make_tab(){
  GATab t{};
  int bladeOf[16]={}; int idxOf[16]={};
  { int p=0;
    for(int g=0; g<=4; ++g)
      for(int m=0; m<16; ++m)
        if(popc4(m)==g){ bladeOf[p]=m; idxOf[m]=p; ++p; }
  }
  int grade[16]={};
  for(int j=0;j<16;++j) grade[j]=popc4(bladeOf[j]);
  bool gpp[125]={}; bool jpp[125]={};
  for(int j=0;j<16;++j) for(int k=0;k<16;++k){
    int mj=bladeOf[j], mk=bladeOf[k];
    if(!(mj&mk&1)){ int i=idxOf[mj^mk]; gpp[(grade[i]*5+grade[j])*5+grade[k]]=true; }
    int cj=15^mj, ck=15^mk;
    if(!(cj&ck)){ int r=mj&mk; int i=idxOf[r]; jpp[(grade[i]*5+grade[j])*5+grade[k]]=true; }
  }
  int gpidx[125]={}; int jpidx[125]={};
  { int c=0; for(int u=0;u<125;++u){ gpidx[u] = gpp[u]? c++ : -1; } t.ngp=c; }
  { int c=0; for(int u=0;u<125;++u){ jpidx[u] = jpp[u]? c++ : -1; } t.njp=c; }
  int q=0;
  for(int j=0;j<16;++j) for(int k=0;k<16;++k){
    int mj=bladeOf[j], mk=bladeOf[k];
    if(!(mj&mk&1)){
      int i=idxOf[mj^mk];
      t.qi[q]=i; t.qj[q]=j; t.qk[q]=k;
      t.qs[q] = swap_par(mj,mk) ? -1.0f : 1.0f;
      t.qgp[q]=1;
      t.qpath[q]=gpidx[(grade[i]*5+grade[j])*5+grade[k]];
      ++q;
    }
  }
  for(int j=0;j<16;++j) for(int k=0;k<16;++k){
    int mj=bladeOf[j], mk=bladeOf[k];
    int cj=15^mj, ck=15^mk;
    if(!(cj&ck)){
      int r=mj&mk; int i=idxOf[r];
      int par = swap_par(mj,15^mj) ^ swap_par(mk,15^mk) ^ swap_par(cj,ck) ^ swap_par(r,15^r);
      t.qi[q]=i; t.qj[q]=j; t.qk[q]=k;
      t.qs[q] = par ? -1.0f : 1.0f;
      t.qgp[q]=0;
      t.qpath[q]=jpidx[(grade[i]*5+grade[j])*5+grade[k]];
      ++q;
    }
  }
  t.nq=q;

  // sort terms by coef index (gp paths first, then jp) so terms sharing one
  // coef value are adjacent -> ONE rolling-register LDS read per unique coef.
  for(int a=1;a<t.nq;++a){
    int ci=t.qi[a], cj2=t.qj[a], ck2=t.qk[a], cg=t.qgp[a], cp=t.qpath[a]; float cs=t.qs[a];
    int key = cg ? cp : 1000+cp;
    int b=a-1;
    while(b>=0){
      int kb = t.qgp[b] ? t.qpath[b] : 1000+t.qpath[b];
      if(kb <= key) break;
      t.qi[b+1]=t.qi[b]; t.qj[b+1]=t.qj[b]; t.qk[b+1]=t.qk[b];
      t.qs[b+1]=t.qs[b]; t.qgp[b+1]=t.qgp[b]; t.qpath[b+1]=t.qpath[b];
      --b;
    }
    t.qi[b+1]=ci; t.qj[b+1]=cj2; t.qk[b+1]=ck2; t.qs[b+1]=cs; t.qgp[b+1]=cg; t.qpath[b+1]=cp;
  }
  for(int a=0;a<t.nq;++a){
    if(a==0){ t.qnew[a]=1; continue; }
    int ka = t.qgp[a]   ? t.qpath[a]   : 1000+t.qpath[a];
    int kb = t.qgp[a-1] ? t.qpath[a-1] : 1000+t.qpath[a-1];
    t.qnew[a] = (ka!=kb) ? 1 : 0;
  }
  return t;
}

constexpr GATab TAB = make_tab();
static_assert(TAB.nq == NQ, "nonzero count mismatch");
static_assert(TAB.ngp > 0 && TAB.njp > 0, "path counts");
constexpr int NGPC = TAB.ngp;
constexpr int NJPC = TAB.njp;
constexpr int GR[16] = {0,1,1,1,1,2,2,2,2,2,2,3,3,3,3,4};

// compact coef tables: odd-padded rows -> per-lane stride odd -> 2-way bank
// aliasing only (free, m136).
constexpr int PADG = (NGPC & 1) ? NGPC : NGPC + 1;
constexpr int PADJ = (NJPC & 1) ? NJPC : NJPC + 1;
constexpr int CGF  = 64 * PADG;          // floats
constexpr int CJF  = 64 * PADJ;          // floats
constexpr int XLF  = 4 * 64 * 16;        // x staging: 4 waves x (64 i x 16 v) = 16 KB
static_assert((CGF + CJF + XLF) * 4 <= 32 * 1024, "5 blocks/CU requires <=32KB");

// ---------------- prep kernels ----------------
// weight table in PACKED FP16: wrph[(i*5+s)*64 + n] = half(w1[g=s]) | half(w2[g=s])<<16
// 20 B/lane/i instead of 48 B -> L2 weight stream 12.6 GB -> 5.25 GB (the
// binding pipe per R16 accounting: 365us -> ~152us). fp16 rel err 2^-11 on
// weights -> output err ~1e-3 << 0.0625 tolerance.
__global__ void prep_wrph(const float* __restrict__ linw, unsigned* __restrict__ wrph){
  int t = blockIdx.x*blockDim.x + threadIdx.x;
  if(t < 64*5*64){
    int n = t & 63;
    int s = (t >> 6) % 5;
    int i = t / 320;
    float w1 = linw[(n*64 + i)*5 + s];
    float w2 = linw[((64+n)*64 + i)*5 + s];
    unsigned short a = __builtin_bit_cast(unsigned short, (_Float16)w1);
    unsigned short b = __builtin_bit_cast(unsigned short, (_Float16)w2);
    wrph[t] = (unsigned)a | ((unsigned)b << 16);
  }
}

// pack gpw/jpw raw into odd-padded rows: cgj[n*PADG+p] , cgj[CGF + n*PADJ+p]
__global__ void prep_cpk(const float* __restrict__ gpw, const float* __restrict__ jpw,
                         float* __restrict__ cgj){
  int n = threadIdx.x; // blockDim = 64, grid = 1
  for(int p=0;p<NGPC;++p) cgj[n*PADG + p] = gpw[n*NGPC + p];
  for(int p=0;p<NJPC;++p) cgj[CGF + n*PADJ + p] = jpw[n*NJPC + p];
}

// ---------------- main fused kernel ----------------
// R16 structure (552us, best-tied) with ONE change: fp16-packed weight table.
//  - L2 weight stream was the binding pipe (12.6 GB ~ 365us > VALU ~280us).
//    fp16 packing: 5 coalesced dword loads + 10 v_cvt_f32_f16 per i
//    (vs 3 dwordx4) -> stream 5.25 GB ~ 152us; VALU becomes the floor.
//  - NB>1 is dead (5 failures: spill x3, latency-serialization x2).
//  - sorted rolling-coef bilinear + sched_barrier(0x7) anti-hoist (R14).
//  - x staged per-wave in LDS, swizzled b128 writes, wave-uniform broadcast
//    f4 reads (0 conflicts, no rdlanes) (R12).
__global__ __launch_bounds__(256)
void main_k(const float* __restrict__ x, const float* __restrict__ cgj,
            const unsigned* __restrict__ wrph, float* __restrict__ out, int B){
  __shared__ float lds[CGF + CJF + XLF];
  float* clg = lds;
  float* clj = lds + CGF;
  float* xl  = lds + CGF + CJF;

  const int tid  = threadIdx.x;
  const int lane = tid & 63;
  const int wv   = tid >> 6;        // 0..3
  const int n    = lane;

  // ---- stage compact coef tables once per block ----
  for(int idx = tid; idx < CGF + CJF; idx += 256) lds[idx] = cgj[idx];
  __syncthreads();

  const int cgbase = n*PADG;
  const int cjbase = n*PADJ;
  float* xw = xl + wv*1024;        // this wave's 64x16 staging region

  for(int base = blockIdx.x*4; base < B; base += gridDim.x*4){
    const int bb = base + wv;

    // ---- stage x: lane writes its channel row (swizzled b128, bank-floor) ----
    if(bb < B){
      const f4* src = (const f4*)(x + ((long)bb*64 + lane)*16);
      #pragma unroll
      for(int r=0;r<4;++r){
        f4 a = __builtin_nontemporal_load(src+r);
        int daddr = (lane*16 + r*4) ^ ((lane&7)<<2);
        *(f4*)(xw + daddr) = a;
      }
    }
    // (per-wave region: in-wave lgkmcnt ordering suffices, no __syncthreads)

    // ---- linear phase: y1[v] = sum_i w1[g(v)]*x[i][v], y2 likewise ----
    float y1[16], y2[16];
    #pragma unroll
    for(int v=0;v<16;++v){ y1[v]=0.f; y2[v]=0.f; }

    #pragma unroll 2
    for(int i=0;i<64;++i){
      const unsigned* wp = wrph + i*320 + n;
      unsigned u0 = wp[0], u1 = wp[64], u2 = wp[128], u3 = wp[192], u4 = wp[256];
      float w1[5], w2[5];
      { hf2 h = __builtin_bit_cast(hf2, u0); w1[0]=(float)h[0]; w2[0]=(float)h[1]; }
      { hf2 h = __builtin_bit_cast(hf2, u1); w1[1]=(float)h[0]; w2[1]=(float)h[1]; }
      { hf2 h = __builtin_bit_cast(hf2, u2); w1[2]=(float)h[0]; w2[2]=(float)h[1]; }
      { hf2 h = __builtin_bit_cast(hf2, u3); w1[3]=(float)h[0]; w2[3]=(float)h[1]; }
      { hf2 h = __builtin_bit_cast(hf2, u4); w1[4]=(float)h[0]; w2[4]=(float)h[1]; }

      // broadcast reads of x[bb][i][0..15]: uniform address, conflict-free
      float xv[16];
      #pragma unroll
      for(int g=0;g<4;++g){
        int raddr = (i*16 + g*4) ^ ((i&7)<<2);
        f4 a = *(const f4*)(xw + raddr);
        xv[g*4+0]=a[0]; xv[g*4+1]=a[1]; xv[g*4+2]=a[2]; xv[g*4+3]=a[3];
      }

      #pragma unroll
      for(int v=0;v<16;++v){
        y1[v] = fmaf(w1[GR[v]], xv[v], y1[v]);
        y2[v] = fmaf(w2[GR[v]], xv[v], y2[v]);
      }
    }

    // ---- bilinear phase: sorted terms, rolling coef register, capped hoist ----
    __builtin_amdgcn_sched_barrier(0x7);
    float acc[16];
    #pragma unroll
    for(int v=0;v<16;++v) acc[v]=y2[v];

    float c = 0.f;
    #pragma unroll
    for(int q=0;q<NQ;++q){
      if(TAB.qnew[q])
        c = TAB.qgp[q] ? clg[cgbase + TAB.qpath[q]] : clj[cjbase + TAB.qpath[q]];
      float prod = y1[TAB.qj[q]] * y2[TAB.qk[q]];
      acc[TAB.qi[q]] = fmaf((TAB.qs[q] < 0.f) ? -c : c, prod, acc[TAB.qi[q]]);
      if((q % 24) == 23) __builtin_amdgcn_sched_barrier(0x7);
    }
    __builtin_amdgcn_sched_barrier(0x7);

    // ---- store (streamed once -> nontemporal) ----
    if(bb < B){
      f4* op = (f4*)(out + ((long)bb*64 + n)*16);
      #pragma unroll
      for(int r=0;r<4;++r){
        f4 o; o[0]=acc[4*r]; o[1]=acc[4*r+1]; o[2]=acc[4*r+2]; o[3]=acc[4*r+3];
        __builtin_nontemporal_store(o, op+r);
      }
    }
  }
}

extern "C" void kernel_launch(void* const* d_in, const int* in_sizes, int n_in,
                              void* d_out, int out_size, void* d_ws, size_t ws_size,
                              hipStream_t stream){
  const float* x    = (const float*)d_in[0];
  const float* gpw  = (const float*)d_in[1];
  const float* jpw  = (const float*)d_in[2];
  const float* linw = (const float*)d_in[3];
  float* outp = (float*)d_out;

  unsigned* wrph = (unsigned*)d_ws;            // 64*5*64 u32 = 80 KB
  float*    cgj  = (float*)(wrph + 64*5*64);   // CGF+CJF floats (~12.5 KB)

  int B = in_sizes[0] / (64*16);

  prep_wrph<<<80, 256, 0, stream>>>(linw, wrph);
  prep_cpk <<<1,  64,  0, stream>>>(gpw, jpw, cgj);
  main_k   <<<2048, 256, 0, stream>>>(x, cgj, wrph, outp, B);
}